// Round 3
// baseline (277.354 us; speedup 1.0000x reference)
//
#include <hip/hip_runtime.h>
#include <hip/hip_bf16.h>
#include <cstdint>

using bf16x8 = __attribute__((ext_vector_type(8))) short;
using f32x4  = __attribute__((ext_vector_type(4))) float;
using f32x16 = __attribute__((ext_vector_type(16))) float;

typedef const __attribute__((address_space(1))) void* gas_ptr;
typedef __attribute__((address_space(3))) void* lds_ptr;

__device__ __forceinline__ short f2bf(float f) {
  unsigned u = __builtin_bit_cast(unsigned, f);
  u += 0x7fffu + ((u >> 16) & 1u);
  return (short)(u >> 16);
}

__device__ __forceinline__ unsigned pack2(float a, float b) {
  unsigned ua = __builtin_bit_cast(unsigned, a);
  ua += 0x7fffu + ((ua >> 16) & 1u);
  unsigned ub = __builtin_bit_cast(unsigned, b);
  ub += 0x7fffu + ((ub >> 16) & 1u);
  return (ua >> 16) | (ub & 0xffff0000u);
}

// ---------- f32 -> bf16 bulk convert (8 elems/thread) ----------
__global__ __launch_bounds__(256) void convert_bf16(const float* __restrict__ src,
                                                    short* __restrict__ dst, int n8) {
  int i = blockIdx.x * 256 + threadIdx.x;
  if (i >= n8) return;
  const float4* s = (const float4*)(src + (size_t)i * 8);
  float4 a = s[0], b = s[1];
  uint4 o;
  o.x = pack2(a.x, a.y); o.y = pack2(a.z, a.w);
  o.z = pack2(b.x, b.y); o.w = pack2(b.z, b.w);
  *(uint4*)(dst + (size_t)i * 8) = o;
}

// ---------- transpose + f32->bf16 convert: dst[C][R] = src[R][C] ----------
__global__ __launch_bounds__(256) void transpose_to_bf16(const float* __restrict__ src,
                                                         short* __restrict__ dst,
                                                         int R, int C) {
  int idx = blockIdx.x * 256 + threadIdx.x;
  if (idx >= R * C) return;
  int c = idx / R;
  int r = idx - c * R;
  dst[(size_t)c * R + r] = f2bf(src[(size_t)r * C + c]);
}

// ---------- GEMM (m97 structure): C[M][N] = A[M][K] * Bt[N][K]^T ----------
template <int OUT_F32>
__global__ __launch_bounds__(256) void gemm_bt(const short* __restrict__ A,
                                               const short* __restrict__ Bt,
                                               void* __restrict__ Cp,
                                               const float* __restrict__ bias,
                                               int Mt, int N, int K) {
  __shared__ short Al[128 * 32];
  __shared__ short Bl[128 * 32];

  const int tid  = threadIdx.x;
  const int lane = tid & 63;
  const int w    = tid >> 6;
  const int c16  = lane & 15;
  const int g    = lane >> 4;
  const int wm   = (w >> 1) * 64;
  const int wn   = (w & 1) * 64;

  const int nwg = gridDim.x;
  const int bid = blockIdx.x;
  const int swz = (bid & 7) * (nwg >> 3) + (bid >> 3);
  const int mtile = swz % Mt;
  const int ntile = swz / Mt;
  const int m0 = mtile * 128;
  const int n0 = ntile * 128;

  const int rsub = lane >> 2;
  const int ksub = (lane & 3) * 8;
  const short* gA0 = A  + (size_t)(m0 + w * 16 + rsub) * K + ksub;
  const short* gA1 = A  + (size_t)(m0 + (w + 4) * 16 + rsub) * K + ksub;
  const short* gB0 = Bt + (size_t)(n0 + w * 16 + rsub) * K + ksub;
  const short* gB1 = Bt + (size_t)(n0 + (w + 4) * 16 + rsub) * K + ksub;
  short* lA0 = Al + w * 512;
  short* lA1 = Al + (w + 4) * 512;
  short* lB0 = Bl + w * 512;
  short* lB1 = Bl + (w + 4) * 512;

  f32x4 acc[4][4] = {};

  for (int k0 = 0; k0 < K; k0 += 32) {
    __builtin_amdgcn_global_load_lds((gas_ptr)(gA0 + k0), (lds_ptr)lA0, 16, 0, 0);
    __builtin_amdgcn_global_load_lds((gas_ptr)(gA1 + k0), (lds_ptr)lA1, 16, 0, 0);
    __builtin_amdgcn_global_load_lds((gas_ptr)(gB0 + k0), (lds_ptr)lB0, 16, 0, 0);
    __builtin_amdgcn_global_load_lds((gas_ptr)(gB1 + k0), (lds_ptr)lB1, 16, 0, 0);
    __syncthreads();

    bf16x8 af[4], bfr[4];
    #pragma unroll
    for (int mt = 0; mt < 4; mt++)
      af[mt] = *(const bf16x8*)&Al[(wm + mt * 16 + c16) * 32 + g * 8];
    #pragma unroll
    for (int nt = 0; nt < 4; nt++)
      bfr[nt] = *(const bf16x8*)&Bl[(wn + nt * 16 + c16) * 32 + g * 8];
    #pragma unroll
    for (int mt = 0; mt < 4; mt++)
      #pragma unroll
      for (int nt = 0; nt < 4; nt++)
        acc[mt][nt] = __builtin_amdgcn_mfma_f32_16x16x32_bf16(af[mt], bfr[nt], acc[mt][nt], 0, 0, 0);
    __syncthreads();
  }

  #pragma unroll
  for (int mt = 0; mt < 4; mt++) {
    #pragma unroll
    for (int nt = 0; nt < 4; nt++) {
      const int row = m0 + wm + mt * 16 + g * 4;
      const int col = n0 + wn + nt * 16 + c16;
      if (OUT_F32) {
        float* C = (float*)Cp;
        const float bb = bias ? bias[col] : 0.f;
        #pragma unroll
        for (int r = 0; r < 4; r++)
          C[(size_t)(row + r) * N + col] = acc[mt][nt][r] + bb;
      } else {
        short* C = (short*)Cp;
        #pragma unroll
        for (int r = 0; r < 4; r++)
          C[(size_t)(row + r) * N + col] = f2bf(acc[mt][nt][r]);
      }
    }
  }
}

// ---------- attention: 1 block per (b, h, fr); n_sp=256, dh=64 ----------
// 32x32x16 swapped-QK^T, in-register softmax + P redistribution (no P LDS).
// LDS: B1 (V rows then K rows, 32 KB) + VT (V^T, 32 KB) = 64 KB -> 2 blocks/CU.
__global__ __launch_bounds__(256, 2) void attn_kernel(const short* __restrict__ qkv,
                                                      short* __restrict__ attn_out) {
  __shared__ short B1[256 * 64];   // stage: V rows, then K rows (XOR-swizzled)
  __shared__ short VT[64 * 256];   // V^T [d][kv] (XOR-swizzled)

  const int tid    = threadIdx.x;
  const int lane   = tid & 63;
  const int w      = tid >> 6;
  const int lane31 = lane & 31;
  const int hi     = lane >> 5;

  const int bid = blockIdx.x;
  const int fr  = bid & 31;
  const int h   = (bid >> 5) & 7;
  const int bb  = bid >> 8;
  const size_t rowbase = (size_t)bb * 8192 + (size_t)fr * 256;
  const short* qb = qkv + rowbase * 1536 + h * 64;
  const short* kb = qb + 512;
  const short* vb = qb + 1024;

  // ---- stage 1: V rows -> B1 (global_load_lds, source pre-swizzled) ----
  {
    const int rl   = lane >> 3;            // row within 8-row group
    const int colb = (lane & 7) * 16;      // byte col within 128B row
    #pragma unroll
    for (int i = 0; i < 8; i++) {
      const int r = w * 64 + i * 8 + rl;
      const short* src = vb + (size_t)r * 1536 + ((colb ^ ((r & 7) << 4)) >> 1);
      __builtin_amdgcn_global_load_lds((gas_ptr)src,
                                       (lds_ptr)(B1 + (w * 64 + i * 8) * 64), 16, 0, 0);
    }
  }
  __syncthreads();

  // ---- stage 2: transpose B1 -> VT (packed u32 writes, conflict-free) ----
  {
    const int p     = tid & 127;     // kv pair index
    const int dhalf = tid >> 7;      // d half: 0 -> d 0..31, 1 -> d 32..63
    const int r0 = 2 * p, r1 = 2 * p + 1;
    #pragma unroll
    for (int i = 0; i < 4; i++) {
      const int cb = dhalf * 64 + i * 16;
      bf16x8 a = *(const bf16x8*)((const char*)B1 + r0 * 128 + (cb ^ ((r0 & 7) << 4)));
      bf16x8 b = *(const bf16x8*)((const char*)B1 + r1 * 128 + (cb ^ ((r1 & 7) << 4)));
      #pragma unroll
      for (int k = 0; k < 8; k++) {
        const int d = dhalf * 32 + i * 8 + k;
        unsigned pk = ((unsigned)(unsigned short)a[k]) |
                      (((unsigned)(unsigned short)b[k]) << 16);
        *(unsigned*)((char*)VT + d * 512 + ((4 * p) ^ ((d & 7) << 4))) = pk;
      }
    }
  }
  __syncthreads();

  // ---- stage 3: K rows -> B1 (reuse buffer) ----
  {
    const int rl   = lane >> 3;
    const int colb = (lane & 7) * 16;
    #pragma unroll
    for (int i = 0; i < 8; i++) {
      const int r = w * 64 + i * 8 + rl;
      const short* src = kb + (size_t)r * 1536 + ((colb ^ ((r & 7) << 4)) >> 1);
      __builtin_amdgcn_global_load_lds((gas_ptr)src,
                                       (lds_ptr)(B1 + (w * 64 + i * 8) * 64), 16, 0, 0);
    }
  }
  __syncthreads();

  const int swl = (lane31 & 7) << 4;  // row-XOR swizzle for this lane's reads

  for (int c = 0; c < 2; c++) {
    const int q0 = c * 128 + w * 32;       // wave's 32 q rows

    // ---- Q fragments (B operand: row = q = lane31, k = 8*hi + j) ----
    const short* qrow = qb + (size_t)(q0 + lane31) * 1536;
    bf16x8 qf[4];
    #pragma unroll
    for (int ds = 0; ds < 4; ds++)
      qf[ds] = *(const bf16x8*)(qrow + ds * 16 + 8 * hi);

    // ---- S^T = K Q^T: D[kv][q], col=lane31=q, row=(reg&3)+8*(reg>>2)+4*hi ----
    f32x16 sacc[8] = {};
    #pragma unroll
    for (int kt = 0; kt < 8; kt++) {
      #pragma unroll
      for (int ds = 0; ds < 4; ds++) {
        bf16x8 kf = *(const bf16x8*)((const char*)B1 + (kt * 32 + lane31) * 128 +
                                     ((ds * 32 + 16 * hi) ^ swl));
        sacc[kt] = __builtin_amdgcn_mfma_f32_32x32x16_bf16(kf, qf[ds], sacc[kt], 0, 0, 0);
      }
    }

    // ---- softmax: lane owns 128 of its q-row's scores; partner = lane^32 ----
    float mx = -1e30f;
    #pragma unroll
    for (int kt = 0; kt < 8; kt++)
      #pragma unroll
      for (int r = 0; r < 16; r++)
        mx = fmaxf(mx, sacc[kt][r]);
    mx = fmaxf(mx, __shfl_xor(mx, 32));
    float sum = 0.f;
    #pragma unroll
    for (int kt = 0; kt < 8; kt++)
      #pragma unroll
      for (int r = 0; r < 16; r++) {
        float p = __expf((sacc[kt][r] - mx) * 0.125f);
        sacc[kt][r] = p;
        sum += p;
      }
    sum += __shfl_xor(sum, 32);
    const float inv = 1.0f / sum;

    // ---- O = P V: per 16-kv block build A-frag in regs (1 xor-32 exchange) ----
    f32x16 o0 = {}, o1 = {};
    #pragma unroll
    for (int m = 0; m < 16; m++) {
      const int nt = m >> 1, rb = (m & 1) * 8;
      unsigned u0 = pack2(sacc[nt][rb + 0] * inv, sacc[nt][rb + 1] * inv);
      unsigned u1 = pack2(sacc[nt][rb + 2] * inv, sacc[nt][rb + 3] * inv);
      unsigned u2 = pack2(sacc[nt][rb + 4] * inv, sacc[nt][rb + 5] * inv);
      unsigned u3 = pack2(sacc[nt][rb + 6] * inv, sacc[nt][rb + 7] * inv);
      int s0 = hi ? (int)u0 : (int)u2;
      int s1 = hi ? (int)u1 : (int)u3;
      int r0 = __shfl_xor(s0, 32);
      int r1 = __shfl_xor(s1, 32);
      int4 paw;
      paw.x = hi ? r0 : (int)u0;
      paw.y = hi ? r1 : (int)u1;
      paw.z = hi ? (int)u2 : r0;
      paw.w = hi ? (int)u3 : r1;
      bf16x8 pa = __builtin_bit_cast(bf16x8, paw);

      bf16x8 v0f = *(const bf16x8*)((const char*)VT + (size_t)lane31 * 512 +
                                    ((m * 32 + 16 * hi) ^ swl));
      o0 = __builtin_amdgcn_mfma_f32_32x32x16_bf16(pa, v0f, o0, 0, 0, 0);
      bf16x8 v1f = *(const bf16x8*)((const char*)VT + (size_t)(32 + lane31) * 512 +
                                    ((m * 32 + 16 * hi) ^ swl));
      o1 = __builtin_amdgcn_mfma_f32_32x32x16_bf16(pa, v1f, o1, 0, 0, 0);
    }

    // ---- store O: D rows = q (reg pattern), cols = d = lane31 ----
    #pragma unroll
    for (int r = 0; r < 16; r++) {
      const int qrel = (r & 3) + 8 * (r >> 2) + 4 * hi;
      const size_t ro = (rowbase + q0 + qrel) * 512 + h * 64;
      attn_out[ro + lane31]      = f2bf(o0[r]);
      attn_out[ro + 32 + lane31] = f2bf(o1[r]);
    }
  }
}

extern "C" void kernel_launch(void* const* d_in, const int* in_sizes, int n_in,
                              void* d_out, int out_size, void* d_ws, size_t ws_size,
                              hipStream_t stream) {
  const float* x     = (const float*)d_in[0];
  const float* w_qkv = (const float*)d_in[1];
  const float* w_out = (const float*)d_in[2];
  const float* b_out = (const float*)d_in[3];
  float* out = (float*)d_out;

  const int M = 32768, DIM = 512, NQKV = 1536;

  short* wqkvT = (short*)d_ws;
  short* woutT = wqkvT + (size_t)NQKV * DIM;
  short* qkvb  = woutT + (size_t)DIM * DIM;
  short* attnb = qkvb + (size_t)M * NQKV;
  short* xbf   = attnb;  // aliased: xbf dead before attn writes

  transpose_to_bf16<<<(DIM * NQKV + 255) / 256, 256, 0, stream>>>(w_qkv, wqkvT, DIM, NQKV);
  transpose_to_bf16<<<(DIM * DIM + 255) / 256, 256, 0, stream>>>(w_out, woutT, DIM, DIM);
  convert_bf16<<<(M * DIM / 8 + 255) / 256, 256, 0, stream>>>(x, xbf, M * DIM / 8);

  gemm_bt<0><<<(M / 128) * (NQKV / 128), 256, 0, stream>>>(xbf, wqkvT, qkvb, nullptr,
                                                           M / 128, NQKV, DIM);

  attn_kernel<<<1024, 256, 0, stream>>>(qkvb, attnb);

  gemm_bt<1><<<(M / 128) * (DIM / 128), 256, 0, stream>>>(attnb, woutT, out, b_out,
                                                          M / 128, DIM, DIM);
}